// Round 5
// baseline (215.315 us; speedup 1.0000x reference)
//
#include <hip/hip_runtime.h>
#include <hip/hip_bf16.h>

// Static config: B=32, H=96, Wd=96, C=64, nW=4, K=3, WS=48, pool=16
#define NPIX 9216   // 96*96

typedef __attribute__((ext_vector_type(8))) short short8v;   // 8 bf16 (4 VGPRs)
typedef __attribute__((ext_vector_type(4))) float floatx4;   // 4 fp32

__device__ __forceinline__ float geluf(float x){
  return 0.5f * x * (1.0f + erff(x * 0.70710678118654752440f));
}
__device__ __forceinline__ float sigm(float x){
  return 1.0f / (1.0f + expf(-x));
}
__device__ __forceinline__ unsigned short f2bf(float f){
  __hip_bfloat16 h = __float2bfloat16(f);
  return *(unsigned short*)&h;
}

// ---------------------------------------------------------------------------
// Kernel A: windowed 48x48 -> 3x3 avg pool.  kern[bw=b*4+w][c][ki*3+kj]
// grid = 128 * 9 = 1152 blocks, 256 threads.
// Block 0 additionally emits po_w MFMA B-fragments for k_conv.
// ---------------------------------------------------------------------------
__global__ __launch_bounds__(256) void k_pool(const float* __restrict__ x,
                                              const float* __restrict__ po_w,
                                              float* __restrict__ kern,
                                              unsigned short* __restrict__ frag_pw)
{
  int blk = blockIdx.x;
  int t = threadIdx.x;
  if (blk == 0){
    for (int idx=t; idx<4096; idx+=256){
      int f = idx >> 9, L = (idx >> 3) & 63, j = idx & 7;
      int nb = f >> 1, kb = f & 1;
      int o = nb*16 + (L & 15);
      int c = kb*32 + ((L >> 4) & 3)*8 + j;
      frag_pw[idx] = f2bf(po_w[o*64 + c]);
    }
  }
  int bw = blk / 9, rem = blk % 9;          // rem = ki*3+kj
  int ki = rem / 3, kj = rem % 3;
  int b = bw >> 2, w = bw & 3;
  int wr = w >> 1, wc = w & 1;
  int cg = t & 15, rw = t >> 4;
  int h = wr*48 + ki*16 + rw;
  int col0 = wc*48 + kj*16;
  size_t base = ((size_t)(b*NPIX + h*96 + col0))*64 + cg*4;
  float a0=0.f,a1=0.f,a2=0.f,a3=0.f;
  #pragma unroll
  for (int j=0;j<16;j++){
    float4 u = *(const float4*)(x + base + (size_t)j*64);
    a0 += u.x; a1 += u.y; a2 += u.z; a3 += u.w;
  }
  __shared__ float red[16*64];
  float* rr = &red[rw*64 + cg*4];
  rr[0]=a0; rr[1]=a1; rr[2]=a2; rr[3]=a3;
  __syncthreads();
  if (t < 64){
    float s = 0.f;
    #pragma unroll
    for (int r=0;r<16;r++) s += red[r*64 + t];
    kern[(size_t)bw*576 + t*9 + rem] = s * (1.0f/256.0f);
  }
}

// ---------------------------------------------------------------------------
// Kernel B (fused SE + rest-graph): one block per batch element b.
// 32 blocks x 512 threads.  Unchanged.
// ---------------------------------------------------------------------------
__global__ __launch_bounds__(512) void k_fuse(const float* __restrict__ kern_ws,
    const float* __restrict__ se_w1, const float* __restrict__ se_b1,
    const float* __restrict__ se_w2, const float* __restrict__ se_b2,
    const float* __restrict__ dc_w,  const float* __restrict__ dc_b,
    const float* __restrict__ l1_w,  const float* __restrict__ l1_b,
    const float* __restrict__ l2_w,  const float* __restrict__ l2_b,
    const float* __restrict__ gkf_w, const float* __restrict__ gkf_b,
    const float* __restrict__ fu_proj_w, const float* __restrict__ fu_proj_b,
    const float* __restrict__ fu_fc1_w,  const float* __restrict__ fu_fc1_b,
    const float* __restrict__ fu_fc2_w,  const float* __restrict__ fu_fc2_b,
    const float* __restrict__ fu_po_w,   const float* __restrict__ fu_po_b,
    float* __restrict__ kc_ws)
{
  int b = blockIdx.x;
  int t = threadIdx.x;
  int lane = t & 63, wv = t >> 6;

  __shared__ float s_w1[64*65];      // [i][o] pad-65
  __shared__ float s_w2[64*65];
  __shared__ float s_pow[64*65];     // fu_po_w transposed [i][c] pad-65
  __shared__ float s_kern[4*64*13];  // [w][c][p] pad-13
  __shared__ float s_t1[4*64*13];    // [w][o][p] pad-13
  __shared__ float s_kse[2304];      // [w][c*9+p]
  __shared__ float s_prj[1088];      // proj_w [g*17 + o*4 + i]
  __shared__ float s_feats[2304];    // [m][p], m = g*4+o
  __shared__ float s_gkf[576];       // [c][p]
  __shared__ float s_xsum[576];      // [i][p]
  __shared__ float s_wwc[256];       // [w][c]
  __shared__ float s_v0[256];
  __shared__ float s_av[256];        // [w][c]
  __shared__ float s_v1[64];
  __shared__ float s_small[64];      // ww1(0..3), h1(16..31), ww2(32..35)

  // S0: stage everything (coalesced, all in flight together)
  for (int idx=t; idx<2304; idx+=512){
    int w = idx/576, cp = idx - w*576;
    int c = cp/9, p = cp - c*9;
    s_kern[(w*64+c)*13+p] = kern_ws[(size_t)(b*4+w)*576 + cp];
  }
  for (int j=t; j<4096; j+=512){
    int o=j>>6, i=j&63;
    s_w1[i*65+o]  = se_w1[j];
    s_w2[i*65+o]  = se_w2[j];
    s_pow[i*65+o] = fu_po_w[j];
  }
  for (int j=t; j<1024; j+=512){ int g=j>>4, oi=j&15; s_prj[g*17+oi] = fu_proj_w[j]; }
  __syncthreads();

  // S1: SE layer 1 (t1 = gelu(W1@kern+b1), 4 windows)  ||  wwc (t<256)
  for (int idx=t; idx<2304; idx+=512){
    int o = idx & 63, wp = idx >> 6;        // wp = w*9+p
    int w = wp/9, p = wp - w*9;
    float acc = se_b1[o];
    #pragma unroll 8
    for (int i=0;i<64;i++) acc += s_w1[i*65+o]*s_kern[(w*64+i)*13+p];
    s_t1[(w*64+o)*13+p] = geluf(acc);
  }
  if (t < 256){
    const float* kr = &s_kern[t*13];        // t = w*64+c
    float s = kr[0]+kr[1]+kr[2]+kr[3]+kr[4]+kr[5]+kr[6]+kr[7]+kr[8];
    s_wwc[t] = s * (1.0f/9.0f);
  }
  __syncthreads();

  // S2: SE layer 2 -> s_kse  ||  dc (t<4, uses wwc)
  for (int idx=t; idx<2304; idx+=512){
    int o = idx & 63, wp = idx >> 6;
    int w = wp/9, p = wp - w*9;
    float acc = se_b2[o];
    #pragma unroll 8
    for (int i=0;i<64;i++) acc += s_w2[i*65+o]*s_t1[(w*64+i)*13+p];
    s_kse[w*576 + o*9 + p] = sigm(acc);
  }
  if (t < 4){
    float acc = dc_b[t];
    #pragma unroll 8
    for (int c=0;c<64;c++) acc += dc_w[t*64+c]*s_wwc[t*64+c];
    s_small[t] = acc;
  }
  __syncthreads();

  // P1: feats (grouped proj + gelu)  ||  l1 (t<16)
  for (int idx=t; idx<2304; idx+=512){
    int g = idx & 63, op = idx >> 6;
    int o = op/9, p = op - o*9;
    float acc = fu_proj_b[g*4+o];
    #pragma unroll
    for (int i=0;i<4;i++){
      int ch = g*4+i;
      acc += s_prj[g*17 + o*4 + i] * s_kse[(ch>>6)*576 + (ch&63)*9 + p];
    }
    s_feats[(g*4+o)*9 + p] = geluf(acc);
  }
  if (t < 16){
    float acc = l1_b[t];
    #pragma unroll
    for (int w=0;w<4;w++) acc += l1_w[t*4+w]*s_small[w];
    s_small[16+t] = geluf(acc);
  }
  __syncthreads();

  // P2: v0 (GAP of feats, t<256)  ||  l2 (threads 256..259)
  if (t < 256){
    const float* f = &s_feats[t*9];
    s_v0[t] = (f[0]+f[1]+f[2]+f[3]+f[4]+f[5]+f[6]+f[7]+f[8]) * (1.0f/9.0f);
  } else if (t < 260){
    int tt = t - 256;
    float acc = l2_b[tt];
    #pragma unroll
    for (int j=0;j<16;j++) acc += l2_w[tt*16+j]*s_small[16+j];
    s_small[32+tt] = sigm(acc);
  }
  __syncthreads();

  // P3: fc1 — 8 waves x 8 outputs, coalesced loads, shuffle reduce
  #pragma unroll
  for (int oi=0; oi<8; oi++){
    int o = wv*8 + oi;
    float v = fu_fc1_w[o*256 +       lane] * s_v0[      lane]
            + fu_fc1_w[o*256 +  64 + lane] * s_v0[ 64 + lane]
            + fu_fc1_w[o*256 + 128 + lane] * s_v0[128 + lane]
            + fu_fc1_w[o*256 + 192 + lane] * s_v0[192 + lane];
    #pragma unroll
    for (int m=32; m>0; m>>=1) v += __shfl_xor(v, m);
    if (lane == 0) s_v1[o] = geluf(v + fu_fc1_b[o]);
  }
  __syncthreads();

  // P4: fc2 (t<256, per-thread register dot)  ||  gkf (all threads)
  if (t < 256){
    const float4* wr = (const float4*)(fu_fc2_w + t*64);
    float acc = 0.f;
    #pragma unroll
    for (int q=0;q<16;q++){
      float4 wq = wr[q];
      acc += wq.x*s_v1[q*4] + wq.y*s_v1[q*4+1] + wq.z*s_v1[q*4+2] + wq.w*s_v1[q*4+3];
    }
    s_av[t] = acc + fu_fc2_b[t];
  }
  for (int idx=t; idx<576; idx+=512){
    int c = idx & 63, p = idx >> 6;
    float acc = gkf_b[c];
    #pragma unroll
    for (int w=0;w<4;w++) acc += gkf_w[c*4+w]*s_kse[w*576+c*9+p]*s_small[32+w];
    s_gkf[c*9+p] = acc;
  }
  __syncthreads();

  // P5: softmax over w per c
  if (t < 64){
    float z0=s_av[t], z1=s_av[64+t], z2=s_av[128+t], z3=s_av[192+t];
    float mx = fmaxf(fmaxf(z0,z1),fmaxf(z2,z3));
    float e0=expf(z0-mx), e1=expf(z1-mx), e2=expf(z2-mx), e3=expf(z3-mx);
    float inv = 1.0f/(e0+e1+e2+e3);
    s_av[t]=e0*inv; s_av[64+t]=e1*inv; s_av[128+t]=e2*inv; s_av[192+t]=e3*inv;
  }
  __syncthreads();

  // P6: xsum[i][p]
  for (int idx=t; idx<576; idx+=512){
    int c = idx & 63, p = idx >> 6;
    float s=0.f;
    #pragma unroll
    for (int w=0;w<4;w++) s += s_kse[w*576+c*9+p]*s_av[w*64+c];
    s_xsum[c*9+p] = s;
  }
  __syncthreads();

  // P7: kc[c][p] = 2*gkf + fu_po_w @ xsum + fu_po_b
  for (int idx=t; idx<576; idx+=512){
    int c = idx & 63, p = idx >> 6;
    float acc = 2.0f*s_gkf[c*9+p] + fu_po_b[c];
    #pragma unroll 8
    for (int i=0;i<64;i++) acc += s_pow[i*65+c]*s_xsum[i*9+p];
    kc_ws[(size_t)b*576 + c*9 + p] = acc;
  }
}

// ---------------------------------------------------------------------------
// Kernel C: depthwise 3x3 + MFMA conv1x1, 8x16 tiles.
// Round-5 changes:
//  - Tile 8x16 (was 8x8): halo read amp 1.41x (was 1.56x); 2304 blocks;
//    16 MFMA/wave (was 8); per-b kc/po_b fixed costs halved.
//  - LDS 18.4 KB: s_tmp[128 px][72] bf16; epilogue restaged in two 64-px
//    halves through the same buffer (s_out 64x68 f32 overlay).
//  - Bijective XCD swizzle (2304 = 8 x 288).
// ---------------------------------------------------------------------------
__global__ __launch_bounds__(256, 4) void k_conv(const float* __restrict__ x,
                                                 const float* __restrict__ kc_ws,
                                                 const unsigned short* __restrict__ frag_pw,
                                                 const float* __restrict__ po_b,
                                                 float* __restrict__ out)
{
  // XCD-chunked swizzle: grid 2304 = 8 XCDs x 288
  int bi_hw = blockIdx.x;
  int bi = (bi_hw & 7) * 288 + (bi_hw >> 3);
  int b = bi / 72, tile = bi % 72;
  int th = tile / 6, tw = tile % 6;        // 12 x 6 tiles of 8x16
  int h0 = th*8, w0 = tw*16;
  int t = threadIdx.x;
  int c = t & 63, rg = t >> 6;
  int r0 = rg*2;

  __shared__ __align__(16) float s_buf[4608];      // 18432 B overlay region
  unsigned short* s_tmp = (unsigned short*)s_buf;  // [128 px][72] bf16
  float* s_out = s_buf;                            // [64 px][68] f32 (per half)

  // kc gather (issues first, overlaps row loads)
  const float* kcb = kc_ws + b*576 + c*9;
  float k0=kcb[0],k1=kcb[1],k2=kcb[2],k3=kcb[3],k4=kcb[4],
        k5=kcb[5],k6=kcb[6],k7=kcb[7],k8=kcb[8];

  // row loads: 4 rows x 18 cols, per-wave coalesced (lane = channel)
  float row[4][18];
  if (th > 0 && th < 11 && tw > 0 && tw < 5){
    const float* xb = x + (((size_t)(b*NPIX + (h0-1+r0)*96 + (w0-1)))<<6) + c;
    #pragma unroll
    for (int rr=0; rr<4; rr++)
      #pragma unroll
      for (int cc=0; cc<18; cc++)
        row[rr][cc] = xb[((size_t)(rr*96 + cc))<<6];
  } else {
    #pragma unroll
    for (int rr=0; rr<4; rr++){
      int hh = h0 - 1 + r0 + rr;
      bool hok = (hh >= 0 && hh < 96);
      #pragma unroll
      for (int cc=0; cc<18; cc++){
        int ww = w0 - 1 + cc;
        float v = 0.f;
        if (hok && ww >= 0 && ww < 96)
          v = x[(((size_t)b*NPIX + hh*96 + ww)<<6) + c];
        row[rr][cc] = v;
      }
    }
  }

  // depthwise 3x3 -> bf16 -> s_tmp  (wave rg writes px rows {2rg, 2rg+1})
  #pragma unroll
  for (int dr=0; dr<2; dr++){
    int pr = r0 + dr;
    #pragma unroll
    for (int pc=0; pc<16; pc++){
      float acc = k0*row[dr+0][pc] + k1*row[dr+0][pc+1] + k2*row[dr+0][pc+2]
                + k3*row[dr+1][pc] + k4*row[dr+1][pc+1] + k5*row[dr+1][pc+2]
                + k6*row[dr+2][pc] + k7*row[dr+2][pc+1] + k8*row[dr+2][pc+2];
      s_tmp[(pr*16 + pc)*72 + c] = f2bf(acc);
    }
  }
  __syncthreads();

  int wv = t >> 6, lane = t & 63;
  int quad = lane >> 4;
  // wave wv computes px range [wv*32, wv*32+32): 2 m-tiles of 16
  floatx4 acc[2][4] = {{{0.f,0.f,0.f,0.f},{0.f,0.f,0.f,0.f},
                        {0.f,0.f,0.f,0.f},{0.f,0.f,0.f,0.f}},
                       {{0.f,0.f,0.f,0.f},{0.f,0.f,0.f,0.f},
                        {0.f,0.f,0.f,0.f},{0.f,0.f,0.f,0.f}}};
  {
    int m0 = wv*32 + (lane & 15);
    #pragma unroll
    for (int mt=0; mt<2; mt++){
      #pragma unroll
      for (int kb=0; kb<2; kb++){
        short8v afrag = *(const short8v*)&s_tmp[(m0 + mt*16)*72 + kb*32 + quad*8];
        #pragma unroll
        for (int nb=0; nb<4; nb++){
          short8v bfrag = *(const short8v*)(frag_pw + (nb*2+kb)*512 + lane*8);
          acc[mt][nb] = __builtin_amdgcn_mfma_f32_16x16x32_bf16(afrag, bfrag, acc[mt][nb], 0, 0, 0);
        }
      }
    }
  }
  __syncthreads();   // all s_tmp consumed; s_out overlay now safe

  // epilogue in two 64-px halves; half h restaged by waves {2h, 2h+1}
  #pragma unroll
  for (int h=0; h<2; h++){
    if ((wv >> 1) == h){
      #pragma unroll
      for (int mt=0; mt<2; mt++){
        #pragma unroll
        for (int nb=0; nb<4; nb++){
          int o = nb*16 + (lane & 15);
          float pb = po_b[o];
          #pragma unroll
          for (int r=0; r<4; r++){
            int pxl = (wv & 1)*32 + mt*16 + quad*4 + r;
            s_out[pxl*68 + o] = acc[mt][nb][r] + pb;
          }
        }
      }
    }
    __syncthreads();
    // coalesced output: 16 lanes per pixel -> one 256B line per pixel
    for (int idx=t; idx<1024; idx+=256){
      int pxl = idx >> 4, c4 = idx & 15;
      int px = h*64 + pxl;
      int hh = h0 + (px >> 4), wwp = w0 + (px & 15);
      floatx4 v = *(const floatx4*)&s_out[pxl*68 + c4*4];
      __builtin_nontemporal_store(v,
          (floatx4*)(out + (((size_t)b*NPIX + hh*96 + wwp)<<6) + c4*4));
    }
    if (h == 0) __syncthreads();
  }
}

// ---------------------------------------------------------------------------
extern "C" void kernel_launch(void* const* d_in, const int* in_sizes, int n_in,
                              void* d_out, int out_size, void* d_ws, size_t ws_size,
                              hipStream_t stream) {
  const float* x        = (const float*)d_in[0];
  const float* se_w1    = (const float*)d_in[1];
  const float* se_b1    = (const float*)d_in[2];
  const float* se_w2    = (const float*)d_in[3];
  const float* se_b2    = (const float*)d_in[4];
  const float* dc_w     = (const float*)d_in[5];
  const float* dc_b     = (const float*)d_in[6];
  const float* l1_w     = (const float*)d_in[7];
  const float* l1_b     = (const float*)d_in[8];
  const float* l2_w     = (const float*)d_in[9];
  const float* l2_b     = (const float*)d_in[10];
  const float* gkf_w    = (const float*)d_in[11];
  const float* gkf_b    = (const float*)d_in[12];
  const float* fu_proj_w= (const float*)d_in[13];
  const float* fu_proj_b= (const float*)d_in[14];
  const float* fu_fc1_w = (const float*)d_in[15];
  const float* fu_fc1_b = (const float*)d_in[16];
  const float* fu_fc2_w = (const float*)d_in[17];
  const float* fu_fc2_b = (const float*)d_in[18];
  const float* fu_po_w  = (const float*)d_in[19];
  const float* fu_po_b  = (const float*)d_in[20];
  const float* po_w     = (const float*)d_in[21];
  const float* po_b     = (const float*)d_in[22];

  float* kern_ws = (float*)d_ws;                                // 128*576 floats
  float* kc_ws   = kern_ws + 73728;                             // 32*576 floats
  unsigned short* frag_pw = (unsigned short*)(kc_ws + 18432);   // 4096 ushort

  k_pool<<<1152, 256, 0, stream>>>(x, po_w, kern_ws, frag_pw);
  k_fuse<<<32, 512, 0, stream>>>(kern_ws,
                                 se_w1, se_b1, se_w2, se_b2,
                                 dc_w, dc_b, l1_w, l1_b, l2_w, l2_b,
                                 gkf_w, gkf_b, fu_proj_w, fu_proj_b,
                                 fu_fc1_w, fu_fc1_b, fu_fc2_w, fu_fc2_b,
                                 fu_po_w, fu_po_b, kc_ws);
  k_conv<<<2304, 256, 0, stream>>>(x, kc_ws, frag_pw, po_b, (float*)d_out);
}

// Round 6
// 211.484 us; speedup vs baseline: 1.0181x; 1.0181x over previous
//
#include <hip/hip_runtime.h>
#include <hip/hip_bf16.h>

// Static config: B=32, H=96, Wd=96, C=64, nW=4, K=3, WS=48, pool=16
#define NPIX 9216   // 96*96

typedef __attribute__((ext_vector_type(8))) short short8v;   // 8 bf16 (4 VGPRs)
typedef __attribute__((ext_vector_type(4))) float floatx4;   // 4 fp32

__device__ __forceinline__ float geluf(float x){
  return 0.5f * x * (1.0f + erff(x * 0.70710678118654752440f));
}
__device__ __forceinline__ float sigm(float x){
  return 1.0f / (1.0f + expf(-x));
}
__device__ __forceinline__ unsigned short f2bf(float f){
  __hip_bfloat16 h = __float2bfloat16(f);
  return *(unsigned short*)&h;
}

// ---------------------------------------------------------------------------
// Kernel A: windowed 48x48 -> 3x3 avg pool.  kern layout [bw][p][c] so the
// final write is one coalesced 256B line (was stride-9 scatter).
// grid = 128 * 9 = 1152 blocks, 256 threads.
// Block 0 additionally emits po_w MFMA B-fragments for k_conv.
// ---------------------------------------------------------------------------
__global__ __launch_bounds__(256) void k_pool(const float* __restrict__ x,
                                              const float* __restrict__ po_w,
                                              float* __restrict__ kern,
                                              unsigned short* __restrict__ frag_pw)
{
  int blk = blockIdx.x;
  int t = threadIdx.x;
  if (blk == 0){
    for (int idx=t; idx<4096; idx+=256){
      int f = idx >> 9, L = (idx >> 3) & 63, j = idx & 7;
      int nb = f >> 1, kb = f & 1;
      int o = nb*16 + (L & 15);
      int c = kb*32 + ((L >> 4) & 3)*8 + j;
      frag_pw[idx] = f2bf(po_w[o*64 + c]);
    }
  }
  int bw = blk / 9, rem = blk % 9;          // rem = ki*3+kj
  int ki = rem / 3, kj = rem % 3;
  int b = bw >> 2, w = bw & 3;
  int wr = w >> 1, wc = w & 1;
  int cg = t & 15, rw = t >> 4;
  int h = wr*48 + ki*16 + rw;
  int col0 = wc*48 + kj*16;
  size_t base = ((size_t)(b*NPIX + h*96 + col0))*64 + cg*4;
  float a0=0.f,a1=0.f,a2=0.f,a3=0.f;
  #pragma unroll
  for (int j=0;j<16;j++){
    float4 u = *(const float4*)(x + base + (size_t)j*64);
    a0 += u.x; a1 += u.y; a2 += u.z; a3 += u.w;
  }
  __shared__ float red[16*64];
  float* rr = &red[rw*64 + cg*4];
  rr[0]=a0; rr[1]=a1; rr[2]=a2; rr[3]=a3;
  __syncthreads();
  if (t < 64){
    float s = 0.f;
    #pragma unroll
    for (int r=0;r<16;r++) s += red[r*64 + t];
    kern[(size_t)bw*576 + rem*64 + t] = s * (1.0f/256.0f);   // [bw][p][c]
  }
}

// ---------------------------------------------------------------------------
// Kernel B (fused SE + rest-graph): one block per batch element b.
// 32 blocks x 512 threads.  Only S0's kern_ws indexing changed ([bw][p][c]).
// ---------------------------------------------------------------------------
__global__ __launch_bounds__(512) void k_fuse(const float* __restrict__ kern_ws,
    const float* __restrict__ se_w1, const float* __restrict__ se_b1,
    const float* __restrict__ se_w2, const float* __restrict__ se_b2,
    const float* __restrict__ dc_w,  const float* __restrict__ dc_b,
    const float* __restrict__ l1_w,  const float* __restrict__ l1_b,
    const float* __restrict__ l2_w,  const float* __restrict__ l2_b,
    const float* __restrict__ gkf_w, const float* __restrict__ gkf_b,
    const float* __restrict__ fu_proj_w, const float* __restrict__ fu_proj_b,
    const float* __restrict__ fu_fc1_w,  const float* __restrict__ fu_fc1_b,
    const float* __restrict__ fu_fc2_w,  const float* __restrict__ fu_fc2_b,
    const float* __restrict__ fu_po_w,   const float* __restrict__ fu_po_b,
    float* __restrict__ kc_ws)
{
  int b = blockIdx.x;
  int t = threadIdx.x;
  int lane = t & 63, wv = t >> 6;

  __shared__ float s_w1[64*65];      // [i][o] pad-65
  __shared__ float s_w2[64*65];
  __shared__ float s_pow[64*65];     // fu_po_w transposed [i][c] pad-65
  __shared__ float s_kern[4*64*13];  // [w][c][p] pad-13
  __shared__ float s_t1[4*64*13];    // [w][o][p] pad-13
  __shared__ float s_kse[2304];      // [w][c*9+p]
  __shared__ float s_prj[1088];      // proj_w [g*17 + o*4 + i]
  __shared__ float s_feats[2304];    // [m][p], m = g*4+o
  __shared__ float s_gkf[576];       // [c][p]
  __shared__ float s_xsum[576];      // [i][p]
  __shared__ float s_wwc[256];       // [w][c]
  __shared__ float s_v0[256];
  __shared__ float s_av[256];        // [w][c]
  __shared__ float s_v1[64];
  __shared__ float s_small[64];      // ww1(0..3), h1(16..31), ww2(32..35)

  // S0: stage everything (coalesced, all in flight together)
  for (int idx=t; idx<2304; idx+=512){
    int w = idx/576, pc = idx - w*576;       // pc = p*64 + c  ([bw][p][c])
    int p = pc >> 6, c = pc & 63;
    s_kern[(w*64+c)*13+p] = kern_ws[(size_t)(b*4+w)*576 + pc];
  }
  for (int j=t; j<4096; j+=512){
    int o=j>>6, i=j&63;
    s_w1[i*65+o]  = se_w1[j];
    s_w2[i*65+o]  = se_w2[j];
    s_pow[i*65+o] = fu_po_w[j];
  }
  for (int j=t; j<1024; j+=512){ int g=j>>4, oi=j&15; s_prj[g*17+oi] = fu_proj_w[j]; }
  __syncthreads();

  // S1: SE layer 1 (t1 = gelu(W1@kern+b1), 4 windows)  ||  wwc (t<256)
  for (int idx=t; idx<2304; idx+=512){
    int o = idx & 63, wp = idx >> 6;        // wp = w*9+p
    int w = wp/9, p = wp - w*9;
    float acc = se_b1[o];
    #pragma unroll 8
    for (int i=0;i<64;i++) acc += s_w1[i*65+o]*s_kern[(w*64+i)*13+p];
    s_t1[(w*64+o)*13+p] = geluf(acc);
  }
  if (t < 256){
    const float* kr = &s_kern[t*13];        // t = w*64+c
    float s = kr[0]+kr[1]+kr[2]+kr[3]+kr[4]+kr[5]+kr[6]+kr[7]+kr[8];
    s_wwc[t] = s * (1.0f/9.0f);
  }
  __syncthreads();

  // S2: SE layer 2 -> s_kse  ||  dc (t<4, uses wwc)
  for (int idx=t; idx<2304; idx+=512){
    int o = idx & 63, wp = idx >> 6;
    int w = wp/9, p = wp - w*9;
    float acc = se_b2[o];
    #pragma unroll 8
    for (int i=0;i<64;i++) acc += s_w2[i*65+o]*s_t1[(w*64+i)*13+p];
    s_kse[w*576 + o*9 + p] = sigm(acc);
  }
  if (t < 4){
    float acc = dc_b[t];
    #pragma unroll 8
    for (int c=0;c<64;c++) acc += dc_w[t*64+c]*s_wwc[t*64+c];
    s_small[t] = acc;
  }
  __syncthreads();

  // P1: feats (grouped proj + gelu)  ||  l1 (t<16)
  for (int idx=t; idx<2304; idx+=512){
    int g = idx & 63, op = idx >> 6;
    int o = op/9, p = op - o*9;
    float acc = fu_proj_b[g*4+o];
    #pragma unroll
    for (int i=0;i<4;i++){
      int ch = g*4+i;
      acc += s_prj[g*17 + o*4 + i] * s_kse[(ch>>6)*576 + (ch&63)*9 + p];
    }
    s_feats[(g*4+o)*9 + p] = geluf(acc);
  }
  if (t < 16){
    float acc = l1_b[t];
    #pragma unroll
    for (int w=0;w<4;w++) acc += l1_w[t*4+w]*s_small[w];
    s_small[16+t] = geluf(acc);
  }
  __syncthreads();

  // P2: v0 (GAP of feats, t<256)  ||  l2 (threads 256..259)
  if (t < 256){
    const float* f = &s_feats[t*9];
    s_v0[t] = (f[0]+f[1]+f[2]+f[3]+f[4]+f[5]+f[6]+f[7]+f[8]) * (1.0f/9.0f);
  } else if (t < 260){
    int tt = t - 256;
    float acc = l2_b[tt];
    #pragma unroll
    for (int j=0;j<16;j++) acc += l2_w[tt*16+j]*s_small[16+j];
    s_small[32+tt] = sigm(acc);
  }
  __syncthreads();

  // P3: fc1 — 8 waves x 8 outputs, coalesced loads, shuffle reduce
  #pragma unroll
  for (int oi=0; oi<8; oi++){
    int o = wv*8 + oi;
    float v = fu_fc1_w[o*256 +       lane] * s_v0[      lane]
            + fu_fc1_w[o*256 +  64 + lane] * s_v0[ 64 + lane]
            + fu_fc1_w[o*256 + 128 + lane] * s_v0[128 + lane]
            + fu_fc1_w[o*256 + 192 + lane] * s_v0[192 + lane];
    #pragma unroll
    for (int m=32; m>0; m>>=1) v += __shfl_xor(v, m);
    if (lane == 0) s_v1[o] = geluf(v + fu_fc1_b[o]);
  }
  __syncthreads();

  // P4: fc2 (t<256, per-thread register dot)  ||  gkf (all threads)
  if (t < 256){
    const float4* wr = (const float4*)(fu_fc2_w + t*64);
    float acc = 0.f;
    #pragma unroll
    for (int q=0;q<16;q++){
      float4 wq = wr[q];
      acc += wq.x*s_v1[q*4] + wq.y*s_v1[q*4+1] + wq.z*s_v1[q*4+2] + wq.w*s_v1[q*4+3];
    }
    s_av[t] = acc + fu_fc2_b[t];
  }
  for (int idx=t; idx<576; idx+=512){
    int c = idx & 63, p = idx >> 6;
    float acc = gkf_b[c];
    #pragma unroll
    for (int w=0;w<4;w++) acc += gkf_w[c*4+w]*s_kse[w*576+c*9+p]*s_small[32+w];
    s_gkf[c*9+p] = acc;
  }
  __syncthreads();

  // P5: softmax over w per c
  if (t < 64){
    float z0=s_av[t], z1=s_av[64+t], z2=s_av[128+t], z3=s_av[192+t];
    float mx = fmaxf(fmaxf(z0,z1),fmaxf(z2,z3));
    float e0=expf(z0-mx), e1=expf(z1-mx), e2=expf(z2-mx), e3=expf(z3-mx);
    float inv = 1.0f/(e0+e1+e2+e3);
    s_av[t]=e0*inv; s_av[64+t]=e1*inv; s_av[128+t]=e2*inv; s_av[192+t]=e3*inv;
  }
  __syncthreads();

  // P6: xsum[i][p]
  for (int idx=t; idx<576; idx+=512){
    int c = idx & 63, p = idx >> 6;
    float s=0.f;
    #pragma unroll
    for (int w=0;w<4;w++) s += s_kse[w*576+c*9+p]*s_av[w*64+c];
    s_xsum[c*9+p] = s;
  }
  __syncthreads();

  // P7: kc[c][p] = 2*gkf + fu_po_w @ xsum + fu_po_b
  for (int idx=t; idx<576; idx+=512){
    int c = idx & 63, p = idx >> 6;
    float acc = 2.0f*s_gkf[c*9+p] + fu_po_b[c];
    #pragma unroll 8
    for (int i=0;i<64;i++) acc += s_pow[i*65+c]*s_xsum[i*9+p];
    kc_ws[(size_t)b*576 + c*9 + p] = acc;
  }
}

// ---------------------------------------------------------------------------
// Kernel C: depthwise 3x3 + MFMA conv1x1.  Round-4 version (measured best):
//  - 8x8 tiles, 4608 blocks, 5 blocks/CU.
//  - Direct-from-global x reads (lane = channel, per-pixel 256B coalesced).
//  - LDS only s_tmp (bf16, 9.2 KB) / s_out (17.4 KB) overlay; 3 barriers.
//  - Coalesced floatx4 nontemporal output stores; bijective XCD swizzle.
// ---------------------------------------------------------------------------
__global__ __launch_bounds__(256, 5) void k_conv(const float* __restrict__ x,
                                                 const float* __restrict__ kc_ws,
                                                 const unsigned short* __restrict__ frag_pw,
                                                 const float* __restrict__ po_b,
                                                 float* __restrict__ out)
{
  // XCD-chunked swizzle: grid 4608 = 8 XCDs x 576; hw round-robin -> chunks
  int bi_hw = blockIdx.x;
  int bi = (bi_hw & 7) * 576 + (bi_hw >> 3);
  int b = bi / 144, tile = bi % 144;
  int th = tile / 12, tw = tile % 12;
  int h0 = th*8, w0 = tw*8;
  int t = threadIdx.x;
  int c = t & 63, rg = t >> 6;
  int r0 = rg*2;

  __shared__ __align__(16) float s_buf[4352];      // 17.4 KB overlay region
  unsigned short* s_tmp = (unsigned short*)s_buf;  // [64 px][72] bf16
  float* s_out = s_buf;                            // [64 px][68] f32

  // kc gather (issues first, overlaps row loads)
  const float* kcb = kc_ws + b*576 + c*9;
  float k0=kcb[0],k1=kcb[1],k2=kcb[2],k3=kcb[3],k4=kcb[4],
        k5=kcb[5],k6=kcb[6],k7=kcb[7],k8=kcb[8];

  // row loads: 4 rows x 10 cols, per-wave coalesced (lane = channel)
  float row[4][10];
  if (th > 0 && th < 11 && tw > 0 && tw < 11){
    const float* xb = x + (((size_t)(b*NPIX + (h0-1+r0)*96 + (w0-1)))<<6) + c;
    #pragma unroll
    for (int rr=0; rr<4; rr++)
      #pragma unroll
      for (int cc=0; cc<10; cc++)
        row[rr][cc] = xb[((size_t)(rr*96 + cc))<<6];
  } else {
    #pragma unroll
    for (int rr=0; rr<4; rr++){
      int hh = h0 - 1 + r0 + rr;
      bool hok = (hh >= 0 && hh < 96);
      #pragma unroll
      for (int cc=0; cc<10; cc++){
        int ww = w0 - 1 + cc;
        float v = 0.f;
        if (hok && ww >= 0 && ww < 96)
          v = x[(((size_t)b*NPIX + hh*96 + ww)<<6) + c];
        row[rr][cc] = v;
      }
    }
  }

  // depthwise 3x3 -> bf16 -> s_tmp
  #pragma unroll
  for (int dr=0; dr<2; dr++){
    int pr = r0 + dr;
    #pragma unroll
    for (int pc=0; pc<8; pc++){
      float acc = k0*row[dr+0][pc] + k1*row[dr+0][pc+1] + k2*row[dr+0][pc+2]
                + k3*row[dr+1][pc] + k4*row[dr+1][pc+1] + k5*row[dr+1][pc+2]
                + k6*row[dr+2][pc] + k7*row[dr+2][pc+1] + k8*row[dr+2][pc+2];
      s_tmp[(pr*8 + pc)*72 + c] = f2bf(acc);
    }
  }
  __syncthreads();

  int wv = t >> 6, lane = t & 63;
  int quad = lane >> 4;
  floatx4 acc[4] = {{0.f,0.f,0.f,0.f},{0.f,0.f,0.f,0.f},
                    {0.f,0.f,0.f,0.f},{0.f,0.f,0.f,0.f}};
  {
    int m = wv*16 + (lane & 15);
    #pragma unroll
    for (int kb=0; kb<2; kb++){
      short8v afrag = *(const short8v*)&s_tmp[m*72 + kb*32 + quad*8];
      #pragma unroll
      for (int nb=0; nb<4; nb++){
        short8v bfrag = *(const short8v*)(frag_pw + (nb*2+kb)*512 + lane*8);
        acc[nb] = __builtin_amdgcn_mfma_f32_16x16x32_bf16(afrag, bfrag, acc[nb], 0, 0, 0);
      }
    }
  }
  __syncthreads();   // all s_tmp consumed; overlay s_out now safe

  {
    #pragma unroll
    for (int nb=0; nb<4; nb++){
      int o = nb*16 + (lane & 15);
      float pb = po_b[o];
      #pragma unroll
      for (int r=0; r<4; r++){
        int px = wv*16 + quad*4 + r;
        s_out[px*68 + o] = acc[nb][r] + pb;
      }
    }
  }
  __syncthreads();

  // coalesced output: 16 lanes per pixel -> one 256B line per pixel
  for (int idx=t; idx<1024; idx+=256){
    int px = idx >> 4, c4 = idx & 15;
    int hh = h0 + (px >> 3), wwp = w0 + (px & 7);
    floatx4 v = *(const floatx4*)&s_out[px*68 + c4*4];
    __builtin_nontemporal_store(v,
        (floatx4*)(out + (((size_t)b*NPIX + hh*96 + wwp)<<6) + c4*4));
  }
}

// ---------------------------------------------------------------------------
extern "C" void kernel_launch(void* const* d_in, const int* in_sizes, int n_in,
                              void* d_out, int out_size, void* d_ws, size_t ws_size,
                              hipStream_t stream) {
  const float* x        = (const float*)d_in[0];
  const float* se_w1    = (const float*)d_in[1];
  const float* se_b1    = (const float*)d_in[2];
  const float* se_w2    = (const float*)d_in[3];
  const float* se_b2    = (const float*)d_in[4];
  const float* dc_w     = (const float*)d_in[5];
  const float* dc_b     = (const float*)d_in[6];
  const float* l1_w     = (const float*)d_in[7];
  const float* l1_b     = (const float*)d_in[8];
  const float* l2_w     = (const float*)d_in[9];
  const float* l2_b     = (const float*)d_in[10];
  const float* gkf_w    = (const float*)d_in[11];
  const float* gkf_b    = (const float*)d_in[12];
  const float* fu_proj_w= (const float*)d_in[13];
  const float* fu_proj_b= (const float*)d_in[14];
  const float* fu_fc1_w = (const float*)d_in[15];
  const float* fu_fc1_b = (const float*)d_in[16];
  const float* fu_fc2_w = (const float*)d_in[17];
  const float* fu_fc2_b = (const float*)d_in[18];
  const float* fu_po_w  = (const float*)d_in[19];
  const float* fu_po_b  = (const float*)d_in[20];
  const float* po_w     = (const float*)d_in[21];
  const float* po_b     = (const float*)d_in[22];

  float* kern_ws = (float*)d_ws;                                // 128*576 floats
  float* kc_ws   = kern_ws + 73728;                             // 32*576 floats
  unsigned short* frag_pw = (unsigned short*)(kc_ws + 18432);   // 4096 ushort

  k_pool<<<1152, 256, 0, stream>>>(x, po_w, kern_ws, frag_pw);
  k_fuse<<<32, 512, 0, stream>>>(kern_ws,
                                 se_w1, se_b1, se_w2, se_b2,
                                 dc_w, dc_b, l1_w, l1_b, l2_w, l2_b,
                                 gkf_w, gkf_b, fu_proj_w, fu_proj_b,
                                 fu_fc1_w, fu_fc1_b, fu_fc2_w, fu_fc2_b,
                                 fu_po_w, fu_po_b, kc_ws);
  k_conv<<<4608, 256, 0, stream>>>(x, kc_ws, frag_pw, po_b, (float*)d_out);
}